// Round 11
// baseline (132.260 us; speedup 1.0000x reference)
//
#include <hip/hip_runtime.h>
#include <stdint.h>

#define IMG 512
// KS2 = sqrt(50/ln2) * 2^11.5 : Schraudolph scale, exponent-field units
// (validated R4-R7, absmax 0.0039 vs threshold 0.02)
#define KS2 24598.990f

typedef float v2f  __attribute__((ext_vector_type(2)));
typedef int   v2i  __attribute__((ext_vector_type(2)));
typedef float v2fu __attribute__((ext_vector_type(2), aligned(4)));  // 4B-aligned 8B load

__device__ __forceinline__ int reflect_idx(int g) {
    int a = abs(g);
    return min(a, 2 * IMG - 2 - a);
}

// Main kernel: interior columns x in [2,509]. Thread = x-pair * 4 rows = 8 px.
// All tap operands are direct 8B global loads (aligned or 4B-offset) -> every
// v_pk operand is a naturally-aligned VGPR pair, zero marshaling movs.
__global__ __launch_bounds__(256, 4) void bilateral_main(
    const float* __restrict__ img, float* __restrict__ out)
{
    const int plane = blockIdx.z;
    const int pi = blockIdx.x * 64 + threadIdx.x;     // pair index 0..255
    const int xp = 2 + 2 * pi;                        // pair start col (even)
    if (xp > 508) return;                             // 2 masked lanes in last x-block
    const int yb = (blockIdx.y * 4 + threadIdx.y) * 4;  // rows yb..yb+3

    const float* __restrict__ src = img + (size_t)plane * (IMG * IMG);

    // Window: 8 rows (yb-2..yb+5, y-reflected) x 5 overlapping pairs
    // P[r][k] = (img[row][xp-2+k], img[row][xp-1+k]) -- 40x global_load_dwordx2
    v2f P[8][5];
    #pragma unroll
    for (int r = 0; r < 8; ++r) {
        const float* rp = src + reflect_idx(yb - 2 + r) * IMG + (xp - 2);
        #pragma unroll
        for (int k = 0; k < 5; ++k)
            P[r][k] = *reinterpret_cast<const v2fu*>(rp + k);
    }

    const uint32_t ksb = __builtin_bit_cast(uint32_t, KS2);
    const uint64_t kspair = (uint64_t)ksb * 0x100000001ULL;  // KS2 in both halves

    float* const dst = out + (size_t)plane * (IMG * IMG) + (size_t)yb * IMG + xp;

    #pragma unroll
    for (int p = 0; p < 4; ++p) {
        v2f qc = P[p + 2][2];
        v2f qcs;
        asm("v_pk_mul_f32 %0, %1, %2" : "=v"(qcs) : "s"(kspair), "v"(qc));
        v2f wsum = {1.0f, 1.0f};   // center tap: e = 1 exactly
        v2f acc  = qc;

        #pragma unroll
        for (int dy = 0; dy < 5; ++dy) {
            #pragma unroll
            for (int dx = 0; dx < 5; ++dx) {
                if (dy == 2 && dx == 2) continue;
                const int r2 = (dx - 2) * (dx - 2) + (dy - 2) * (dy - 2);
                // Ktap = float_bias + 2^23*log2(spatial_w), exponent-field units
                const float    Kf    = (float)(1065353216.0 - 6051101.63118 * (double)r2);
                const uint32_t kb    = __builtin_bit_cast(uint32_t, Kf);
                const uint64_t kpair = (uint64_t)kb * 0x100000001ULL;

                v2f qt = P[p + dy][dx];
                v2f ds, t;
                // ds = KS2*qt - qcs   (scale folded into the diff FMA)
                asm("v_pk_fma_f32 %0, %1, %2, %3 neg_lo:[0,0,1] neg_hi:[0,0,1]"
                    : "=v"(ds) : "s"(kspair), "v"(qt), "v"(qcs));
                // t = Ktap - ds*ds
                asm("v_pk_fma_f32 %0, %1, %1, %2 neg_lo:[1,0,0] neg_hi:[1,0,0]"
                    : "=v"(t) : "v"(ds), "s"(kpair));
                v2i iv = __builtin_convertvector(t, v2i);  // 2x v_cvt_i32_f32
                v2f e  = __builtin_bit_cast(v2f, iv);      // e ~ 2^arg (free)
                asm("v_pk_add_f32 %0, %1, %0" : "+v"(wsum) : "v"(e));
                asm("v_pk_fma_f32 %0, %1, %2, %0" : "+v"(acc) : "v"(e), "v"(qt));
            }
        }
        v2f res;
        res.x = acc.x * __builtin_amdgcn_rcpf(wsum.x);  // wsum >= 1, eps not needed
        res.y = acc.y * __builtin_amdgcn_rcpf(wsum.y);
        *reinterpret_cast<v2f*>(dst + p * IMG) = res;
    }
}

// Edge kernel: columns {0,1,510,511} (0.8% of px), scalar with full reflect.
__global__ __launch_bounds__(256) void bilateral_edge(
    const float* __restrict__ img, float* __restrict__ out)
{
    const int idx = blockIdx.x * 256 + threadIdx.x;
    const int plane = idx >> 11;           // / (512*4)
    const int rem   = idx & 2047;
    const int y  = rem >> 2;
    const int xi = rem & 3;
    const int x  = (xi < 2) ? xi : (IMG - 4 + xi);   // 0,1,510,511

    const float* __restrict__ src = img + (size_t)plane * (IMG * IMG);
    const float qc = src[y * IMG + x];
    float wsum = 1.0f, acc = qc;

    #pragma unroll
    for (int dy = 0; dy < 5; ++dy) {
        const int yy = reflect_idx(y + dy - 2) * IMG;
        #pragma unroll
        for (int dx = 0; dx < 5; ++dx) {
            if (dy == 2 && dx == 2) continue;
            const int r2 = (dx - 2) * (dx - 2) + (dy - 2) * (dy - 2);
            const float Kf = (float)(1065353216.0 - 6051101.63118 * (double)r2);
            const float qt = src[yy + reflect_idx(x + dx - 2)];
            const float d  = (qt - qc) * KS2;
            const float t  = __builtin_fmaf(-d, d, Kf);
            const float e  = __builtin_bit_cast(float, (int)t);
            wsum += e;
            acc = __builtin_fmaf(e, qt, acc);
        }
    }
    out[(size_t)plane * (IMG * IMG) + y * IMG + x] = acc * __builtin_amdgcn_rcpf(wsum);
}

extern "C" void kernel_launch(void* const* d_in, const int* in_sizes, int n_in,
                              void* d_out, int out_size, void* d_ws, size_t ws_size,
                              hipStream_t stream) {
    const float* img = (const float*)d_in[0];
    float* out = (float*)d_out;
    const int planes = in_sizes[0] / (IMG * IMG);  // 48

    dim3 gmain(4, 32, planes);      // x: 256 pairs (254 used), y: 32*16 rows
    dim3 bmain(64, 4, 1);
    bilateral_main<<<gmain, bmain, 0, stream>>>(img, out);

    const int edge_threads = planes * IMG * 4;
    bilateral_edge<<<edge_threads / 256, 256, 0, stream>>>(img, out);
}